// Round 14
// baseline (187.994 us; speedup 1.0000x reference)
//
#include <hip/hip_runtime.h>
#include <hip/hip_cooperative_groups.h>
namespace cg = cooperative_groups;

// SpectralPooling via split-bf16 MFMA.  [r14 = r12 math, FUSED:
// one cooperative kernel, phase1 = k1 slices (grid-stride 8192),
// grid.sync(), phase2 = k2 tiles (1536). Deletes launch gap + k2 ramp;
// phase2 reads y2 from the local (XCD-pinned) L2 phase1 just filled.
// Fallback: if cooperative launch fails, run the two r12 kernels.]
// Layouts (m89): A-op row=lane&15, k=8*(lane>>4)+j. B-op col=lane&15, same k.
// D: col=lane&15, row=4*(lane>>4)+reg.

typedef __attribute__((ext_vector_type(8))) short short8;
typedef __attribute__((ext_vector_type(8))) unsigned short u16x8;
typedef __attribute__((ext_vector_type(4))) float f32x4;
typedef __attribute__((ext_vector_type(2))) unsigned int u32x2;

// ======================= compile-time matrix table =======================
constexpr double CPI   = 3.14159265358979323846264338327950288;
constexpr double CS48  = 0.20412414523193150818310700622549;   // sqrt(2/48)
constexpr double CS64  = 0.17677669529663688110021109052621;   // sqrt(2/64)
constexpr double CISQ2 = 0.70710678118654752440084436210485;   // 1/sqrt(2)

constexpr double ccos_raw(double x) {            // |x| <= pi/2, Taylor
    double x2 = x * x, term = 1.0, s = 1.0;
    for (int n = 1; n <= 13; ++n) { term *= -x2 / double((2 * n - 1) * (2 * n)); s += term; }
    return s;
}
constexpr double ccos(double x) {                // 0 <= x < 2*pi
    if (x > CPI) x = 2.0 * CPI - x;
    double sgn = 1.0;
    if (x > CPI * 0.5) { x = CPI - x; sgn = -1.0; }
    return sgn * ccos_raw(x);
}
constexpr unsigned short f2bf_c(float f) {       // RNE float->bf16 bits
    if (f == 0.0f) return 0;
    int sign = 0; double x = f;
    if (x < 0) { sign = 1; x = -x; }
    int e = 0;
    while (x >= 2.0) { x *= 0.5; ++e; }
    while (x < 1.0)  { x *= 2.0; --e; }
    double v = x * 128.0;
    long iv = (long)v; double fr = v - (double)iv;
    long m = iv;
    if (fr > 0.5 || (fr == 0.5 && (iv & 1))) ++m;
    if (m == 256) { m = 128; ++e; }
    return (unsigned short)((sign << 15) | ((e + 127) << 7) | (int)(m - 128));
}

struct CosTab48 { double v[192];
    constexpr CosTab48() : v{} { for (int m = 0; m < 192; ++m) v[m] = ccos(CPI * m / 96.0) * CS48; } };
struct CosTab64 { double v[256];
    constexpr CosTab64() : v{} { for (int m = 0; m < 256; ++m) v[m] = ccos(CPI * m / 128.0) * CS64; } };
constexpr CosTab48 CT48{};
constexpr CosTab64 CT64{};

struct Part512 { unsigned short hi[512];
    constexpr Part512(int p) : hi{} {
        int ks = p / 3, t = p % 3;
        for (int i = 0; i < 512; ++i) {
            int j = i & 7, l = i >> 3;
            int k = 8 * (l >> 4) + j + 32 * ks;
            int a = 16 * t + (l & 15);
            double s = 0.0;
            for (int kk = 0; kk < 32; ++kk) {
                int m48 = ((2 * a + 1) * kk) % 192;
                int m64 = ((2 * k + 1) * kk) % 256;
                double c48 = CT48.v[m48], c64 = CT64.v[m64];
                if (kk == 0) { c48 *= CISQ2; c64 *= CISQ2; }
                s += c48 * c64;
            }
            hi[i] = f2bf_c((float)s);
        }
    }
};
constexpr Part512 TP0(0), TP1(1), TP2(2), TP3(3), TP4(4), TP5(5);

struct AllTbl { alignas(16) unsigned short v[6][512];
    constexpr AllTbl() : v{} {
        for (int i = 0; i < 512; ++i) v[0][i] = TP0.hi[i];
        for (int i = 0; i < 512; ++i) v[1][i] = TP1.hi[i];
        for (int i = 0; i < 512; ++i) v[2][i] = TP2.hi[i];
        for (int i = 0; i < 512; ++i) v[3][i] = TP3.hi[i];
        for (int i = 0; i < 512; ++i) v[4][i] = TP4.hi[i];
        for (int i = 0; i < 512; ++i) v[5][i] = TP5.hi[i];
    }
};
__device__ constexpr AllTbl g_tbl{};

static __device__ __forceinline__ short8 ldtbl(int ks, int t, int l) {
    return *(const short8*)&g_tbl.v[ks * 3 + t][l * 8];
}

static __device__ __forceinline__ unsigned short f2bf(float f) {
    unsigned int u = __float_as_uint(f);
    u += 0x7fffu + ((u >> 16) & 1u);          // RNE
    return (unsigned short)(u >> 16);
}

// ---------------- phase-1 body: one (bc,d) slice, W then H ----------------
#define SC_S 72   // u16 row stride: 144 B rows (16B-aligned), b128 reads clean
static __device__ __forceinline__ void k1_body(int task, const float* __restrict__ x,
                                               unsigned short* __restrict__ y2,
                                               unsigned short* sC, int tid) {
    // XCD-pinned remap: xcd = task%8 owns bc in [xcd*16, xcd*16+16)
    const int xcd = task & 7;
    const int idx = task >> 3;
    const int bc = xcd * 16 + (idx & 15);
    const int d  = idx >> 4;
    const int blk = bc * 64 + d;

    const int g = __builtin_amdgcn_readfirstlane(tid >> 6);
    const int l = tid & 63;
    const int r = l & 15;
    const int kq = l >> 4;

    f32x4 z = {0.f, 0.f, 0.f, 0.f};
    f32x4 acc0 = z, acc1 = z, acc2 = z;
    const float* xb = x + (unsigned)(blk * 4096 + (16 * g + r) * 64 + kq * 8);
    #pragma unroll
    for (int ks = 0; ks < 2; ++ks) {
        f32x4 xa = __builtin_nontemporal_load((const f32x4*)(xb + 32 * ks));
        f32x4 xc = __builtin_nontemporal_load((const f32x4*)(xb + 32 * ks + 4));
        float v[8] = {xa[0], xa[1], xa[2], xa[3], xc[0], xc[1], xc[2], xc[3]};
        short8 xh, xl;
        #pragma unroll
        for (int j = 0; j < 8; ++j) {
            unsigned int u = __float_as_uint(v[j]);           // truncation split
            float rem = v[j] - __uint_as_float(u & 0xffff0000u);
            xh[j] = (short)(u >> 16);
            xl[j] = (short)(__float_as_uint(rem) >> 16);
        }
        #pragma unroll
        for (int t = 0; t < 3; ++t) {
            short8 wh = ldtbl(ks, t, l);
            f32x4 a = (t == 0) ? acc0 : (t == 1) ? acc1 : acc2;
            a = __builtin_amdgcn_mfma_f32_16x16x32_bf16(xh, wh, a, 0, 0, 0);
            a = __builtin_amdgcn_mfma_f32_16x16x32_bf16(xl, wh, a, 0, 0, 0);
            if (t == 0) acc0 = a; else if (t == 1) acc1 = a; else acc2 = a;
        }
    }
    #pragma unroll
    for (int t = 0; t < 3; ++t) {
        f32x4 a = (t == 0) ? acc0 : (t == 1) ? acc1 : acc2;
        u32x2 pk;
        pk[0] = (unsigned int)f2bf(a[0]) | ((unsigned int)f2bf(a[1]) << 16);
        pk[1] = (unsigned int)f2bf(a[2]) | ((unsigned int)f2bf(a[3]) << 16);
        *(u32x2*)&sC[(16 * t + r) * SC_S + 16 * g + 4 * kq] = pk;
    }
    __syncthreads();

    auto loadA = [&](int m, int ks) -> short8 {
        return *(const short8*)&sC[(16 * m + r) * SC_S + 8 * kq + 32 * ks];
    };
    auto storeY = [&](int m, int n, f32x4 c) {
        u32x2 pk;
        pk[0] = (unsigned int)f2bf(c[0]) | ((unsigned int)f2bf(c[1]) << 16);
        pk[1] = (unsigned int)f2bf(c[2]) | ((unsigned int)f2bf(c[3]) << 16);
        *(u32x2*)(y2 + (unsigned)(blk * 2304 + (16 * n + r) * 48 + 16 * m + 4 * kq)) = pk;
    };

    if (g < 3) {
        f32x4 c0 = z, c1 = z;
        #pragma unroll
        for (int ks = 0; ks < 2; ++ks) {
            short8 ah = ldtbl(ks, g, l);
            c0 = __builtin_amdgcn_mfma_f32_16x16x32_bf16(loadA(0, ks), ah, c0, 0, 0, 0);
            c1 = __builtin_amdgcn_mfma_f32_16x16x32_bf16(loadA(1, ks), ah, c1, 0, 0, 0);
        }
        storeY(0, g, c0);
        storeY(1, g, c1);
    } else {
        f32x4 t0 = z, t1 = z, t2 = z;
        #pragma unroll
        for (int ks = 0; ks < 2; ++ks) {
            short8 ca = loadA(2, ks);
            t0 = __builtin_amdgcn_mfma_f32_16x16x32_bf16(ca, ldtbl(ks, 0, l), t0, 0, 0, 0);
            t1 = __builtin_amdgcn_mfma_f32_16x16x32_bf16(ca, ldtbl(ks, 1, l), t1, 0, 0, 0);
            t2 = __builtin_amdgcn_mfma_f32_16x16x32_bf16(ca, ldtbl(ks, 2, l), t2, 0, 0, 0);
        }
        storeY(2, 0, t0);
        storeY(2, 1, t1);
        storeY(2, 2, t2);
    }
}

// ---------------- phase-2 body: one (bc,quad) D-transform tile ----------------
static __device__ __forceinline__ void k2_body(int task, const unsigned short* __restrict__ y2,
                                               float* __restrict__ out,
                                               unsigned short* sY, int tid) {
    const int xcd = task & 7;
    const int idx = task >> 3;             // 0..191 = 16 bc_lo * 12 quad
    const int bc = xcd * 16 + idx / 12;
    const int quad = idx % 12;

    const unsigned short* yb = y2 + (unsigned)(bc * 147456 + quad * 4 * 48);
    unsigned int* S32 = (unsigned int*)sY;
    const int dh = tid & 31;               // d-pair index, d0 = 2*dh
    #pragma unroll
    for (int jj = 0; jj < 3; ++jj) {
        int cp = (tid >> 5) + 8 * jj;      // 0..23
        int a1l = cp & 3, q = cp >> 2;     // q 0..5
        int m = q >> 1, c0 = 8 * (q & 1);
        u16x8 v0 = *(const u16x8*)(yb + (unsigned)((2 * dh) * 2304 + a1l * 48 + q * 8));
        u16x8 v1 = *(const u16x8*)(yb + (unsigned)((2 * dh + 1) * 2304 + a1l * 48 + q * 8));
        unsigned int base = (unsigned)(((a1l * 3 + m) * 16 + c0) * 32);
        #pragma unroll
        for (int e = 0; e < 8; ++e)
            S32[base + e * 32 + (dh ^ (e << 2))] =
                (unsigned int)v0[e] | ((unsigned int)v1[e] << 16);
    }
    __syncthreads();

    const int g = __builtin_amdgcn_readfirstlane(tid >> 6);
    const int l = tid & 63;
    const int r = l & 15;
    const int kq = l >> 4;
    const int a1 = quad * 4 + g;

    short8 th[2][3];
    #pragma unroll
    for (int ks = 0; ks < 2; ++ks)
        #pragma unroll
        for (int n = 0; n < 3; ++n) th[ks][n] = ldtbl(ks, n, l);

    f32x4 z = {0.f, 0.f, 0.f, 0.f};
    f32x4 acc[3][3];
    #pragma unroll
    for (int m = 0; m < 3; ++m)
        #pragma unroll
        for (int n = 0; n < 3; ++n) acc[m][n] = z;

    #pragma unroll
    for (int m = 0; m < 3; ++m) {
        #pragma unroll
        for (int ks = 0; ks < 2; ++ks) {
            short8 ya = *(const short8*)&sY[(unsigned)(((g * 3 + m) * 16 + r) * 64
                                            + ((8 * kq + 32 * ks) ^ ((r & 7) << 3)))];
            #pragma unroll
            for (int n = 0; n < 3; ++n)
                acc[m][n] = __builtin_amdgcn_mfma_f32_16x16x32_bf16(ya, th[ks][n], acc[m][n], 0, 0, 0);
        }
    }

    #pragma unroll
    for (int m = 0; m < 3; ++m)
        #pragma unroll
        for (int n = 0; n < 3; ++n) {
            f32x4 v = acc[m][n];
            float* dst = out + ((size_t)(bc * 48 + 16 * n + r) * 48 + a1) * 48 + 16 * m + 4 * kq;
            __builtin_nontemporal_store(v, (f32x4*)dst);   // out never re-read
        }
}

// ---------------- fused cooperative kernel ----------------
__global__ __launch_bounds__(256, 6) void fused(const float* __restrict__ x,
                                                unsigned short* __restrict__ y2,
                                                float* __restrict__ out) {
    __shared__ __align__(16) unsigned short smem[12288];   // 24 KB (phase2 size)
    const int tid = threadIdx.x;

    for (unsigned t = blockIdx.x; t < 8192; t += gridDim.x) {
        k1_body((int)t, x, y2, smem, tid);
        __syncthreads();                    // protect smem before next slice
    }
    cg::this_grid().sync();                 // all y2 visible device-wide
    for (unsigned s = blockIdx.x; s < 1536; s += gridDim.x) {
        k2_body((int)s, y2, out, smem, tid);
        __syncthreads();
    }
}

// ---------------- fallback standalone kernels (r12 path) ----------------
__global__ __launch_bounds__(256) void k1_wh(const float* __restrict__ x,
                                             unsigned short* __restrict__ y2) {
    __shared__ __align__(16) unsigned short sC[48 * SC_S];
    k1_body(blockIdx.x, x, y2, sC, threadIdx.x);
}
__global__ __launch_bounds__(256) void k2_d(const unsigned short* __restrict__ y2,
                                            float* __restrict__ out) {
    __shared__ __align__(16) unsigned short sY[12288];
    k2_body(blockIdx.x, y2, out, sY, threadIdx.x);
}

extern "C" void kernel_launch(void* const* d_in, const int* in_sizes, int n_in,
                              void* d_out, int out_size, void* d_ws, size_t ws_size,
                              hipStream_t stream) {
    const float* x = (const float*)d_in[0];
    float* out = (float*)d_out;
    unsigned short* y2 = (unsigned short*)d_ws;     // 36.75 MiB bf16

    // co-resident grid size (host-side query, no stream ops; deterministic)
    int maxB = 0;
    hipError_t qe = hipOccupancyMaxActiveBlocksPerMultiprocessor(&maxB, fused, 256, 0);
    int G = 1536;
    if (qe == hipSuccess && maxB >= 1 && maxB < 6) G = maxB * 256;  // 256 CUs; multiple of 8

    void* args[] = { (void*)&x, (void*)&y2, (void*)&out };
    hipError_t le = hipLaunchCooperativeKernel((const void*)fused, dim3(G), dim3(256),
                                               args, 0, stream);
    if (le != hipSuccess) {
        // fallback: two-kernel r12 path (same math)
        k1_wh<<<128 * 64, 256, 0, stream>>>(x, y2);
        k2_d<<<128 * 12, 256, 0, stream>>>(y2, out);
    }
}

// Round 15
// 65.295 us; speedup vs baseline: 2.8792x; 2.8792x over previous
//
#include <hip/hip_runtime.h>

// SpectralPooling via split-bf16 MFMA.  [r15 = r10 math byte-identical +
// pure cache hints: NT loads for x (single-use stream) in k1, NT stores for
// out (never re-read) in k2 -- frees L2 for the y2 producer->consumer path.]
// y = A x_D A x_H A x_W x, A = 48x64 composed (truncate32 + iDCT48) matrix.
// All stages v_mfma_f32_16x16x32_bf16. Layouts (m89): A-op row=lane&15,
// k=8*(lane>>4)+j. B-op col=lane&15, same k. D: col=lane&15, row=4*(lane>>4)+reg.
// Ledger (measured): k1 = 28us (traffic floor 27, r9 probe). k2 = 19us
// single-shot / 12.8 steady (r11/r13 probes; floor ~10). Gaps ~6.
// Total mandatory HBM: x 134 + out 57 + y2 74 = 265 MB -> 42us @ 6.3TB/s.

typedef __attribute__((ext_vector_type(8))) short short8;
typedef __attribute__((ext_vector_type(8))) unsigned short u16x8;
typedef __attribute__((ext_vector_type(4))) float f32x4;
typedef __attribute__((ext_vector_type(2))) unsigned int u32x2;

// ======================= compile-time matrix table =======================
constexpr double CPI   = 3.14159265358979323846264338327950288;
constexpr double CS48  = 0.20412414523193150818310700622549;   // sqrt(2/48)
constexpr double CS64  = 0.17677669529663688110021109052621;   // sqrt(2/64)
constexpr double CISQ2 = 0.70710678118654752440084436210485;   // 1/sqrt(2)

constexpr double ccos_raw(double x) {            // |x| <= pi/2, Taylor
    double x2 = x * x, term = 1.0, s = 1.0;
    for (int n = 1; n <= 13; ++n) { term *= -x2 / double((2 * n - 1) * (2 * n)); s += term; }
    return s;
}
constexpr double ccos(double x) {                // 0 <= x < 2*pi
    if (x > CPI) x = 2.0 * CPI - x;
    double sgn = 1.0;
    if (x > CPI * 0.5) { x = CPI - x; sgn = -1.0; }
    return sgn * ccos_raw(x);
}
constexpr unsigned short f2bf_c(float f) {       // RNE float->bf16 bits
    if (f == 0.0f) return 0;
    int sign = 0; double x = f;
    if (x < 0) { sign = 1; x = -x; }
    int e = 0;
    while (x >= 2.0) { x *= 0.5; ++e; }
    while (x < 1.0)  { x *= 2.0; --e; }
    double v = x * 128.0;
    long iv = (long)v; double fr = v - (double)iv;
    long m = iv;
    if (fr > 0.5 || (fr == 0.5 && (iv & 1))) ++m;
    if (m == 256) { m = 128; ++e; }
    return (unsigned short)((sign << 15) | ((e + 127) << 7) | (int)(m - 128));
}

struct CosTab48 { double v[192];
    constexpr CosTab48() : v{} { for (int m = 0; m < 192; ++m) v[m] = ccos(CPI * m / 96.0) * CS48; } };
struct CosTab64 { double v[256];
    constexpr CosTab64() : v{} { for (int m = 0; m < 256; ++m) v[m] = ccos(CPI * m / 128.0) * CS64; } };
constexpr CosTab48 CT48{};
constexpr CosTab64 CT64{};

struct Part512 { unsigned short hi[512];
    constexpr Part512(int p) : hi{} {
        int ks = p / 3, t = p % 3;
        for (int i = 0; i < 512; ++i) {
            int j = i & 7, l = i >> 3;
            int k = 8 * (l >> 4) + j + 32 * ks;
            int a = 16 * t + (l & 15);
            double s = 0.0;
            for (int kk = 0; kk < 32; ++kk) {
                int m48 = ((2 * a + 1) * kk) % 192;
                int m64 = ((2 * k + 1) * kk) % 256;
                double c48 = CT48.v[m48], c64 = CT64.v[m64];
                if (kk == 0) { c48 *= CISQ2; c64 *= CISQ2; }
                s += c48 * c64;
            }
            hi[i] = f2bf_c((float)s);
        }
    }
};
constexpr Part512 TP0(0), TP1(1), TP2(2), TP3(3), TP4(4), TP5(5);

struct AllTbl { alignas(16) unsigned short v[6][512];
    constexpr AllTbl() : v{} {
        for (int i = 0; i < 512; ++i) v[0][i] = TP0.hi[i];
        for (int i = 0; i < 512; ++i) v[1][i] = TP1.hi[i];
        for (int i = 0; i < 512; ++i) v[2][i] = TP2.hi[i];
        for (int i = 0; i < 512; ++i) v[3][i] = TP3.hi[i];
        for (int i = 0; i < 512; ++i) v[4][i] = TP4.hi[i];
        for (int i = 0; i < 512; ++i) v[5][i] = TP5.hi[i];
    }
};
__device__ constexpr AllTbl g_tbl{};

static __device__ __forceinline__ short8 ldtbl(int ks, int t, int l) {
    return *(const short8*)&g_tbl.v[ks * 3 + t][l * 8];
}

static __device__ __forceinline__ unsigned short f2bf(float f) {
    unsigned int u = __float_as_uint(f);
    u += 0x7fffu + ((u >> 16) & 1u);          // RNE
    return (unsigned short)(u >> 16);
}

// ---------------- K1: per (bc,d) slice: W then H, both on MFMA ----------------
// [frozen at its 28 us traffic floor (r9); only x loads gain NT hint]
#define SC_S 72   // u16 row stride: 144 B rows (16B-aligned), b128 reads clean
__global__ __launch_bounds__(256) void k1_wh(const float* __restrict__ x,
                                             unsigned short* __restrict__ y2) {
    __shared__ unsigned short sC[48 * SC_S];   // C1^T [a2][h], single bf16, 6.9 KB

    const int tid = threadIdx.x;
    const int blk = blockIdx.x;                         // bc*64 + d
    const int g = __builtin_amdgcn_readfirstlane(tid >> 6);
    const int l = tid & 63;
    const int r = l & 15;
    const int kq = l >> 4;

    // ---- stage W: C1[h][a2] = sum_w x[h][w] * At[w][a2]; wave g owns h rows [16g,16g+16)
    f32x4 z = {0.f, 0.f, 0.f, 0.f};
    f32x4 acc0 = z, acc1 = z, acc2 = z;
    const float* xb = x + (unsigned)(blk * 4096 + (16 * g + r) * 64 + kq * 8);
    #pragma unroll
    for (int ks = 0; ks < 2; ++ks) {
        f32x4 xa = __builtin_nontemporal_load((const f32x4*)(xb + 32 * ks));
        f32x4 xc = __builtin_nontemporal_load((const f32x4*)(xb + 32 * ks + 4));
        float v[8] = {xa[0], xa[1], xa[2], xa[3], xc[0], xc[1], xc[2], xc[3]};
        short8 xh, xl;
        #pragma unroll
        for (int j = 0; j < 8; ++j) {
            // truncation split: hi = chop(f), lo = chop(f - hi)
            unsigned int u = __float_as_uint(v[j]);
            float rem = v[j] - __uint_as_float(u & 0xffff0000u);
            xh[j] = (short)(u >> 16);
            xl[j] = (short)(__float_as_uint(rem) >> 16);
        }
        #pragma unroll
        for (int t = 0; t < 3; ++t) {
            short8 wh = ldtbl(ks, t, l);
            f32x4 a = (t == 0) ? acc0 : (t == 1) ? acc1 : acc2;
            a = __builtin_amdgcn_mfma_f32_16x16x32_bf16(xh, wh, a, 0, 0, 0);
            a = __builtin_amdgcn_mfma_f32_16x16x32_bf16(xl, wh, a, 0, 0, 0);
            if (t == 0) acc0 = a; else if (t == 1) acc1 = a; else acc2 = a;
        }
    }
    // store C1^T single-bf16 to LDS: lane holds C1[h=16g+4kq+rr][a2=16t+r]
    #pragma unroll
    for (int t = 0; t < 3; ++t) {
        f32x4 a = (t == 0) ? acc0 : (t == 1) ? acc1 : acc2;
        u32x2 pk;
        pk[0] = (unsigned int)f2bf(a[0]) | ((unsigned int)f2bf(a[1]) << 16);
        pk[1] = (unsigned int)f2bf(a[2]) | ((unsigned int)f2bf(a[3]) << 16);
        *(u32x2*)&sC[(16 * t + r) * SC_S + 16 * g + 4 * kq] = pk;   // 4 consecutive h
    }
    __syncthreads();

    // ---- stage H (swapped operands): C2[a2][a1] = sum_h C1[h][a2] * At[h][a1]
    auto loadA = [&](int m, int ks) -> short8 {
        return *(const short8*)&sC[(16 * m + r) * SC_S + 8 * kq + 32 * ks];
    };
    auto storeY = [&](int m, int n, f32x4 c) {
        // a2 = 16m + 4kq + rr (consecutive), a1 = 16n + r
        u32x2 pk;
        pk[0] = (unsigned int)f2bf(c[0]) | ((unsigned int)f2bf(c[1]) << 16);
        pk[1] = (unsigned int)f2bf(c[2]) | ((unsigned int)f2bf(c[3]) << 16);
        *(u32x2*)(y2 + (unsigned)(blk * 2304 + (16 * n + r) * 48 + 16 * m + 4 * kq)) = pk;
    };

    if (g < 3) {
        f32x4 c0 = z, c1 = z;
        #pragma unroll
        for (int ks = 0; ks < 2; ++ks) {
            short8 ah = ldtbl(ks, g, l);
            c0 = __builtin_amdgcn_mfma_f32_16x16x32_bf16(loadA(0, ks), ah, c0, 0, 0, 0);
            c1 = __builtin_amdgcn_mfma_f32_16x16x32_bf16(loadA(1, ks), ah, c1, 0, 0, 0);
        }
        storeY(0, g, c0);
        storeY(1, g, c1);
    } else {
        f32x4 t0 = z, t1 = z, t2 = z;
        #pragma unroll
        for (int ks = 0; ks < 2; ++ks) {
            short8 ca = loadA(2, ks);
            t0 = __builtin_amdgcn_mfma_f32_16x16x32_bf16(ca, ldtbl(ks, 0, l), t0, 0, 0, 0);
            t1 = __builtin_amdgcn_mfma_f32_16x16x32_bf16(ca, ldtbl(ks, 1, l), t1, 0, 0, 0);
            t2 = __builtin_amdgcn_mfma_f32_16x16x32_bf16(ca, ldtbl(ks, 2, l), t2, 0, 0, 0);
        }
        storeY(2, 0, t0);
        storeY(2, 1, t1);
        storeY(2, 2, t2);
    }
}

// ---------------- K2: D-transform, swizzled-transpose staging ----------------
// out[bc][a0][a1][a2] = sum_d y2[bc][d][a1][a2] * At[d][a0]
// [only change vs r10: NT store for out]
__global__ __launch_bounds__(256) void k2_d(const unsigned short* __restrict__ y2,
                                            float* __restrict__ out) {
    __shared__ unsigned short sY[4 * 3 * 16 * 64];   // 24 KB

    const int tid = threadIdx.x;
    const int blk = blockIdx.x;            // bc*12 + quad
    const int bc = blk / 12;
    const int quad = blk % 12;

    const unsigned short* yb = y2 + (unsigned)(bc * 147456 + quad * 4 * 48);
    unsigned int* S32 = (unsigned int*)sY;
    const int dh = tid & 31;               // d-pair index, d0 = 2*dh
    #pragma unroll
    for (int jj = 0; jj < 3; ++jj) {
        int cp = (tid >> 5) + 8 * jj;      // 0..23
        int a1l = cp & 3, q = cp >> 2;     // q 0..5
        int m = q >> 1, c0 = 8 * (q & 1);
        u16x8 v0 = *(const u16x8*)(yb + (unsigned)((2 * dh) * 2304 + a1l * 48 + q * 8));
        u16x8 v1 = *(const u16x8*)(yb + (unsigned)((2 * dh + 1) * 2304 + a1l * 48 + q * 8));
        unsigned int base = (unsigned)(((a1l * 3 + m) * 16 + c0) * 32);
        #pragma unroll
        for (int e = 0; e < 8; ++e)
            S32[base + e * 32 + (dh ^ (e << 2))] =
                (unsigned int)v0[e] | ((unsigned int)v1[e] << 16);
    }
    __syncthreads();

    const int g = __builtin_amdgcn_readfirstlane(tid >> 6);   // wave -> a1 local
    const int l = tid & 63;
    const int r = l & 15;
    const int kq = l >> 4;
    const int a1 = quad * 4 + g;

    // hoist B-frags (constant table)
    short8 th[2][3];
    #pragma unroll
    for (int ks = 0; ks < 2; ++ks)
        #pragma unroll
        for (int n = 0; n < 3; ++n) th[ks][n] = ldtbl(ks, n, l);

    f32x4 z = {0.f, 0.f, 0.f, 0.f};
    f32x4 acc[3][3];
    #pragma unroll
    for (int m = 0; m < 3; ++m)
        #pragma unroll
        for (int n = 0; n < 3; ++n) acc[m][n] = z;

    #pragma unroll
    for (int m = 0; m < 3; ++m) {
        #pragma unroll
        for (int ks = 0; ks < 2; ++ks) {
            // A-frag: row=a2=16m+r, k=d=8kq+32ks+j -> one swizzled b128
            short8 ya = *(const short8*)&sY[(unsigned)(((g * 3 + m) * 16 + r) * 64
                                            + ((8 * kq + 32 * ks) ^ ((r & 7) << 3)))];
            #pragma unroll
            for (int n = 0; n < 3; ++n)
                acc[m][n] = __builtin_amdgcn_mfma_f32_16x16x32_bf16(ya, th[ks][n], acc[m][n], 0, 0, 0);
        }
    }

    // ---- store: lane (kq,r), tile (m,n): out[a0=16n+r][a1][a2=16m+4kq+rr]
    #pragma unroll
    for (int m = 0; m < 3; ++m)
        #pragma unroll
        for (int n = 0; n < 3; ++n) {
            f32x4 v = acc[m][n];
            float* dst = out + ((size_t)(bc * 48 + 16 * n + r) * 48 + a1) * 48 + 16 * m + 4 * kq;
            __builtin_nontemporal_store(v, (f32x4*)dst);   // out never re-read
        }
}

extern "C" void kernel_launch(void* const* d_in, const int* in_sizes, int n_in,
                              void* d_out, int out_size, void* d_ws, size_t ws_size,
                              hipStream_t stream) {
    const float* x = (const float*)d_in[0];
    float* out = (float*)d_out;

    unsigned short* y2 = (unsigned short*)d_ws;     // 36.75 MiB bf16

    k1_wh<<<128 * 64, 256, 0, stream>>>(x, y2);
    k2_d<<<128 * 12, 256, 0, stream>>>(y2, out);
}

// Round 16
// 52.682 us; speedup vs baseline: 3.5685x; 1.2394x over previous
//
#include <hip/hip_runtime.h>

// SpectralPooling via split-bf16 MFMA.  [r16 = r10 EXACT REVERT — best measured
// (52.8us). r15's NT hints regressed +24% (gfx950 'nt' demotes cache residency);
// r14 coop fusion regressed; r12 XCD-pin neutral. Ledger: k1=28us (at 27us HBM
// floor, r9 probe), k2=19us (12.8 steady, r11/r13 probes), gaps ~6us.
// Practical floor ~48us; this is within ~10% of it.]
// y = A x_D A x_H A x_W x, A = 48x64 composed (truncate32 + iDCT48) matrix.
// All stages v_mfma_f32_16x16x32_bf16. Layouts (m89): A-op row=lane&15,
// k=8*(lane>>4)+j. B-op col=lane&15, same k. D: col=lane&15, row=4*(lane>>4)+reg.

typedef __attribute__((ext_vector_type(8))) short short8;
typedef __attribute__((ext_vector_type(8))) unsigned short u16x8;
typedef __attribute__((ext_vector_type(4))) float f32x4;
typedef __attribute__((ext_vector_type(4))) unsigned int u32x4;
typedef __attribute__((ext_vector_type(2))) unsigned int u32x2;

// ======================= compile-time matrix table =======================
constexpr double CPI   = 3.14159265358979323846264338327950288;
constexpr double CS48  = 0.20412414523193150818310700622549;   // sqrt(2/48)
constexpr double CS64  = 0.17677669529663688110021109052621;   // sqrt(2/64)
constexpr double CISQ2 = 0.70710678118654752440084436210485;   // 1/sqrt(2)

constexpr double ccos_raw(double x) {            // |x| <= pi/2, Taylor
    double x2 = x * x, term = 1.0, s = 1.0;
    for (int n = 1; n <= 13; ++n) { term *= -x2 / double((2 * n - 1) * (2 * n)); s += term; }
    return s;
}
constexpr double ccos(double x) {                // 0 <= x < 2*pi
    if (x > CPI) x = 2.0 * CPI - x;
    double sgn = 1.0;
    if (x > CPI * 0.5) { x = CPI - x; sgn = -1.0; }
    return sgn * ccos_raw(x);
}
constexpr unsigned short f2bf_c(float f) {       // RNE float->bf16 bits
    if (f == 0.0f) return 0;
    int sign = 0; double x = f;
    if (x < 0) { sign = 1; x = -x; }
    int e = 0;
    while (x >= 2.0) { x *= 0.5; ++e; }
    while (x < 1.0)  { x *= 2.0; --e; }
    double v = x * 128.0;
    long iv = (long)v; double fr = v - (double)iv;
    long m = iv;
    if (fr > 0.5 || (fr == 0.5 && (iv & 1))) ++m;
    if (m == 256) { m = 128; ++e; }
    return (unsigned short)((sign << 15) | ((e + 127) << 7) | (int)(m - 128));
}

struct CosTab48 { double v[192];
    constexpr CosTab48() : v{} { for (int m = 0; m < 192; ++m) v[m] = ccos(CPI * m / 96.0) * CS48; } };
struct CosTab64 { double v[256];
    constexpr CosTab64() : v{} { for (int m = 0; m < 256; ++m) v[m] = ccos(CPI * m / 128.0) * CS64; } };
constexpr CosTab48 CT48{};
constexpr CosTab64 CT64{};

// Part p = (ks*3 + t): 512 bf16 entries: idx = l*8+j, k = 8*(l>>4)+j+32*ks,
// a = 16*t+(l&15); value = hi-bf16 of sum_{kk<32} c48[a,kk]*c64[k,kk].
struct Part512 { unsigned short hi[512];
    constexpr Part512(int p) : hi{} {
        int ks = p / 3, t = p % 3;
        for (int i = 0; i < 512; ++i) {
            int j = i & 7, l = i >> 3;
            int k = 8 * (l >> 4) + j + 32 * ks;
            int a = 16 * t + (l & 15);
            double s = 0.0;
            for (int kk = 0; kk < 32; ++kk) {
                int m48 = ((2 * a + 1) * kk) % 192;
                int m64 = ((2 * k + 1) * kk) % 256;
                double c48 = CT48.v[m48], c64 = CT64.v[m64];
                if (kk == 0) { c48 *= CISQ2; c64 *= CISQ2; }
                s += c48 * c64;
            }
            hi[i] = f2bf_c((float)s);
        }
    }
};
constexpr Part512 TP0(0), TP1(1), TP2(2), TP3(3), TP4(4), TP5(5);

struct AllTbl { alignas(16) unsigned short v[6][512];
    constexpr AllTbl() : v{} {
        for (int i = 0; i < 512; ++i) v[0][i] = TP0.hi[i];
        for (int i = 0; i < 512; ++i) v[1][i] = TP1.hi[i];
        for (int i = 0; i < 512; ++i) v[2][i] = TP2.hi[i];
        for (int i = 0; i < 512; ++i) v[3][i] = TP3.hi[i];
        for (int i = 0; i < 512; ++i) v[4][i] = TP4.hi[i];
        for (int i = 0; i < 512; ++i) v[5][i] = TP5.hi[i];
    }
};
__device__ constexpr AllTbl g_tbl{};

static __device__ __forceinline__ short8 ldtbl(int ks, int t, int l) {
    return *(const short8*)&g_tbl.v[ks * 3 + t][l * 8];
}

static __device__ __forceinline__ unsigned short f2bf(float f) {
    unsigned int u = __float_as_uint(f);
    u += 0x7fffu + ((u >> 16) & 1u);          // RNE
    return (unsigned short)(u >> 16);
}

// ---------------- K1: per (bc,d) slice: W then H, both on MFMA ----------------
#define SC_S 72   // u16 row stride: 144 B rows (16B-aligned), b128 reads clean
__global__ __launch_bounds__(256) void k1_wh(const float* __restrict__ x,
                                             unsigned short* __restrict__ y2) {
    __shared__ unsigned short sC[48 * SC_S];   // C1^T [a2][h], single bf16, 6.9 KB

    const int tid = threadIdx.x;
    const int blk = blockIdx.x;                         // bc*64 + d
    const int g = __builtin_amdgcn_readfirstlane(tid >> 6);
    const int l = tid & 63;
    const int r = l & 15;
    const int kq = l >> 4;

    // ---- stage W: C1[h][a2] = sum_w x[h][w] * At[w][a2]; wave g owns h rows [16g,16g+16)
    f32x4 z = {0.f, 0.f, 0.f, 0.f};
    f32x4 acc0 = z, acc1 = z, acc2 = z;
    const float* xb = x + (unsigned)(blk * 4096 + (16 * g + r) * 64 + kq * 8);
    #pragma unroll
    for (int ks = 0; ks < 2; ++ks) {
        float4 xa = *(const float4*)(xb + 32 * ks);
        float4 xc = *(const float4*)(xb + 32 * ks + 4);
        float v[8] = {xa.x, xa.y, xa.z, xa.w, xc.x, xc.y, xc.z, xc.w};
        short8 xh, xl;
        #pragma unroll
        for (int j = 0; j < 8; ++j) {
            // truncation split: hi = chop(f), lo = chop(f - hi)
            unsigned int u = __float_as_uint(v[j]);
            float rem = v[j] - __uint_as_float(u & 0xffff0000u);
            xh[j] = (short)(u >> 16);
            xl[j] = (short)(__float_as_uint(rem) >> 16);
        }
        #pragma unroll
        for (int t = 0; t < 3; ++t) {
            short8 wh = ldtbl(ks, t, l);
            f32x4 a = (t == 0) ? acc0 : (t == 1) ? acc1 : acc2;
            a = __builtin_amdgcn_mfma_f32_16x16x32_bf16(xh, wh, a, 0, 0, 0);
            a = __builtin_amdgcn_mfma_f32_16x16x32_bf16(xl, wh, a, 0, 0, 0);
            if (t == 0) acc0 = a; else if (t == 1) acc1 = a; else acc2 = a;
        }
    }
    // store C1^T single-bf16 to LDS: lane holds C1[h=16g+4kq+rr][a2=16t+r]
    #pragma unroll
    for (int t = 0; t < 3; ++t) {
        f32x4 a = (t == 0) ? acc0 : (t == 1) ? acc1 : acc2;
        u32x2 pk;
        pk[0] = (unsigned int)f2bf(a[0]) | ((unsigned int)f2bf(a[1]) << 16);
        pk[1] = (unsigned int)f2bf(a[2]) | ((unsigned int)f2bf(a[3]) << 16);
        *(u32x2*)&sC[(16 * t + r) * SC_S + 16 * g + 4 * kq] = pk;   // 4 consecutive h
    }
    __syncthreads();

    // ---- stage H (swapped operands): C2[a2][a1] = sum_h C1[h][a2] * At[h][a1]
    auto loadA = [&](int m, int ks) -> short8 {
        return *(const short8*)&sC[(16 * m + r) * SC_S + 8 * kq + 32 * ks];
    };
    auto storeY = [&](int m, int n, f32x4 c) {
        // a2 = 16m + 4kq + rr (consecutive), a1 = 16n + r
        u32x2 pk;
        pk[0] = (unsigned int)f2bf(c[0]) | ((unsigned int)f2bf(c[1]) << 16);
        pk[1] = (unsigned int)f2bf(c[2]) | ((unsigned int)f2bf(c[3]) << 16);
        *(u32x2*)(y2 + (unsigned)(blk * 2304 + (16 * n + r) * 48 + 16 * m + 4 * kq)) = pk;
    };

    if (g < 3) {
        f32x4 c0 = z, c1 = z;
        #pragma unroll
        for (int ks = 0; ks < 2; ++ks) {
            short8 ah = ldtbl(ks, g, l);
            c0 = __builtin_amdgcn_mfma_f32_16x16x32_bf16(loadA(0, ks), ah, c0, 0, 0, 0);
            c1 = __builtin_amdgcn_mfma_f32_16x16x32_bf16(loadA(1, ks), ah, c1, 0, 0, 0);
        }
        storeY(0, g, c0);
        storeY(1, g, c1);
    } else {
        f32x4 t0 = z, t1 = z, t2 = z;
        #pragma unroll
        for (int ks = 0; ks < 2; ++ks) {
            short8 ca = loadA(2, ks);
            t0 = __builtin_amdgcn_mfma_f32_16x16x32_bf16(ca, ldtbl(ks, 0, l), t0, 0, 0, 0);
            t1 = __builtin_amdgcn_mfma_f32_16x16x32_bf16(ca, ldtbl(ks, 1, l), t1, 0, 0, 0);
            t2 = __builtin_amdgcn_mfma_f32_16x16x32_bf16(ca, ldtbl(ks, 2, l), t2, 0, 0, 0);
        }
        storeY(2, 0, t0);
        storeY(2, 1, t1);
        storeY(2, 2, t2);
    }
}

// ---------------- K2: D-transform, swizzled-transpose staging ----------------
// out[bc][a0][a1][a2] = sum_d y2[bc][d][a1][a2] * At[d][a0]
__global__ __launch_bounds__(256) void k2_d(const unsigned short* __restrict__ y2,
                                            float* __restrict__ out) {
    __shared__ unsigned short sY[4 * 3 * 16 * 64];   // 24 KB

    const int tid = threadIdx.x;
    const int blk = blockIdx.x;            // bc*12 + quad
    const int bc = blk / 12;
    const int quad = blk % 12;

    const unsigned short* yb = y2 + (unsigned)(bc * 147456 + quad * 4 * 48);
    unsigned int* S32 = (unsigned int*)sY;
    const int dh = tid & 31;               // d-pair index, d0 = 2*dh
    #pragma unroll
    for (int jj = 0; jj < 3; ++jj) {
        int cp = (tid >> 5) + 8 * jj;      // 0..23
        int a1l = cp & 3, q = cp >> 2;     // q 0..5
        int m = q >> 1, c0 = 8 * (q & 1);
        u16x8 v0 = *(const u16x8*)(yb + (unsigned)((2 * dh) * 2304 + a1l * 48 + q * 8));
        u16x8 v1 = *(const u16x8*)(yb + (unsigned)((2 * dh + 1) * 2304 + a1l * 48 + q * 8));
        unsigned int base = (unsigned)(((a1l * 3 + m) * 16 + c0) * 32);
        #pragma unroll
        for (int e = 0; e < 8; ++e)
            S32[base + e * 32 + (dh ^ (e << 2))] =
                (unsigned int)v0[e] | ((unsigned int)v1[e] << 16);
    }
    __syncthreads();

    const int g = __builtin_amdgcn_readfirstlane(tid >> 6);   // wave -> a1 local
    const int l = tid & 63;
    const int r = l & 15;
    const int kq = l >> 4;
    const int a1 = quad * 4 + g;

    // hoist B-frags (constant table)
    short8 th[2][3];
    #pragma unroll
    for (int ks = 0; ks < 2; ++ks)
        #pragma unroll
        for (int n = 0; n < 3; ++n) th[ks][n] = ldtbl(ks, n, l);

    f32x4 z = {0.f, 0.f, 0.f, 0.f};
    f32x4 acc[3][3];
    #pragma unroll
    for (int m = 0; m < 3; ++m)
        #pragma unroll
        for (int n = 0; n < 3; ++n) acc[m][n] = z;

    #pragma unroll
    for (int m = 0; m < 3; ++m) {
        #pragma unroll
        for (int ks = 0; ks < 2; ++ks) {
            // A-frag: row=a2=16m+r, k=d=8kq+32ks+j -> one swizzled b128
            short8 ya = *(const short8*)&sY[(unsigned)(((g * 3 + m) * 16 + r) * 64
                                            + ((8 * kq + 32 * ks) ^ ((r & 7) << 3)))];
            #pragma unroll
            for (int n = 0; n < 3; ++n)
                acc[m][n] = __builtin_amdgcn_mfma_f32_16x16x32_bf16(ya, th[ks][n], acc[m][n], 0, 0, 0);
        }
    }

    // ---- store: lane (kq,r), tile (m,n): out[a0=16n+r][a1][a2=16m+4kq+rr]
    #pragma unroll
    for (int m = 0; m < 3; ++m)
        #pragma unroll
        for (int n = 0; n < 3; ++n) {
            float4 v;
            v.x = acc[m][n][0]; v.y = acc[m][n][1]; v.z = acc[m][n][2]; v.w = acc[m][n][3];
            float* dst = out + ((size_t)(bc * 48 + 16 * n + r) * 48 + a1) * 48 + 16 * m + 4 * kq;
            *(float4*)dst = v;
        }
}

extern "C" void kernel_launch(void* const* d_in, const int* in_sizes, int n_in,
                              void* d_out, int out_size, void* d_ws, size_t ws_size,
                              hipStream_t stream) {
    const float* x = (const float*)d_in[0];
    float* out = (float*)d_out;

    unsigned short* y2 = (unsigned short*)d_ws;     // 36.75 MiB bf16

    k1_wh<<<128 * 64, 256, 0, stream>>>(x, y2);
    k2_d<<<128 * 12, 256, 0, stream>>>(y2, out);
}